// Round 9
// baseline (99.037 us; speedup 1.0000x reference)
//
#include <hip/hip_runtime.h>

// ---------------------------------------------------------------------------
// Model_51453708206406: fast_pos_embed_interpolate + MRoPE cos/sin (f32 out).
// Outputs concatenated: [46080,1152] pe | [46080,128] cos | [46080,128] sin.
// Static grid: {1,64,64},{4,48,48},{8,32,64},{16,32,32}; merge m=2, G=35.
//
// v9: LDS-staged bilinear. Patch block = (image, token-row, 72-ch chunk);
// stages table rows {hf,hc} x 35 cols x 72 ch (20.2 KB) into LDS once, then
// serves all 4-corner reads from LDS. Cuts issued fabric reads 175->57 MB
// (the only lever left: R3-R7 all sit at (W+R)/7.5TB/s regardless of store
// policy/ordering). Rope identical to v6-best. Frame dedup kept.
// ---------------------------------------------------------------------------

typedef float fx4 __attribute__((ext_vector_type(4)));

__device__ __forceinline__ void nt_store4(float* p, fx4 v) {
    __builtin_nontemporal_store(v, (fx4*)p);
}

// ---- patch: b in [0, H*16); hrow = b>>4, chunk = b&15 (72 channels) -------
template <int T, int H, int W, int OFF>
__device__ __forceinline__ void patch_body(int b, const float* __restrict__ tab,
                                           float* __restrict__ out) {
    constexpr int HW = H * W;
    constexpr int WB = W / 2;

    __shared__ float lds[2 * 35 * 72];    // [half][wcol][ch]  20.2 KB

    int hrow  = b >> 4;
    int c0    = (b & 15) * 72;            // channel base of this chunk

    float hx = (float)hrow * (float)(34.0 / (H - 1));
    int   hf = (int)hx;
    float dh = hx - (float)hf;
    int   hc = min(hf + 1, 34);

    // stage: 2 halves x 35 cols x 18 fx4  (1260 fx4 over 256 threads)
    for (int s = (int)threadIdx.x; s < 2 * 35 * 18; s += 256) {
        int half = s / (35 * 18);
        int r2   = s - half * (35 * 18);
        int wcol = r2 / 18;
        int q    = r2 - wcol * 18;
        int hrt  = half ? hc : hf;
        fx4 v = *((const fx4*)(tab + (size_t)(hrt * 35 + wcol) * 1152 + c0) + q);
        *((fx4*)&lds[half * (35 * 72) + wcol * 72 + (q << 2)]) = v;
    }
    __syncthreads();

    float omdh = 1.f - dh;

    // compute: W cols x 18 quads
    for (int t = (int)threadIdx.x; t < W * 18; t += 256) {
        int colw = t / 18;
        int q    = t - colw * 18;

        float wx = (float)colw * (float)(34.0 / (W - 1));
        int   wf = (int)wx;
        float dw = wx - (float)wf;
        int   wc = min(wf + 1, 34);

        float w00 = omdh * (1.f - dw);
        float w01 = omdh * dw;
        float w10 = dh * (1.f - dw);
        float w11 = dh * dw;

        const fx4 a = *((const fx4*)&lds[            wf * 72 + (q << 2)]);
        const fx4 bq= *((const fx4*)&lds[            wc * 72 + (q << 2)]);
        const fx4 c = *((const fx4*)&lds[35 * 72 +   wf * 72 + (q << 2)]);
        const fx4 d = *((const fx4*)&lds[35 * 72 +   wc * 72 + (q << 2)]);

        fx4 o = w00 * a + w01 * bq + w10 * c + w11 * d;

        // forward merged-order token index: row=hrow, col=colw
        int tok = (((hrow >> 1) * WB + (colw >> 1)) << 2)
                + ((hrow & 1) << 1) + (colw & 1);

        float* dst = out + (size_t)(OFF + tok) * 1152 + c0 + (q << 2);
        #pragma unroll
        for (int f = 0; f < T; ++f)       // frames are identical copies
            nt_store4(dst + (size_t)f * (HW * 1152), o);
    }
}

// ---- rope: fully frame-split, one (token, channel-quad) per thread --------
template <int T, int H, int W, int OFF>
__device__ __forceinline__ void rope_body(int b, const float* __restrict__ invf,
                                          float* __restrict__ cosO,
                                          float* __restrict__ sinO) {
    constexpr int HW = H * W;
    constexpr int WB = W / 2;

    int idx = b * 256 + (int)threadIdx.x; // < T*HW*16 (mult of 256)
    int tok = idx >> 4;
    int l4  = idx & 15;                   // channel-quad, d0 = 4*l4 in [0,64)
    int rem = tok % HW;                   // frame-local (frames identical)

    int j  = rem & 1;
    int i  = (rem >> 1) & 1;
    int blk = rem >> 2;
    int bw = blk % WB;
    int bh = blk / WB;
    int row = (bh << 1) + i;
    int col = (bw << 1) + j;

    float fp = (float)((l4 < 8) ? row : col);   // d0<32 -> row else col
    fx4 iv = ((const fx4*)invf)[l4 & 7];

    float s0, c0, s1, c1, s2, c2, s3, c3;
    __sincosf(fp * iv.x, &s0, &c0);
    __sincosf(fp * iv.y, &s1, &c1);
    __sincosf(fp * iv.z, &s2, &c2);
    __sincosf(fp * iv.w, &s3, &c3);
    fx4 cv = {c0, c1, c2, c3};
    fx4 sv = {s0, s1, s2, s3};

    size_t base = (size_t)(OFF + tok) * 128 + (l4 << 2);
    nt_store4(cosO + base,      cv);      // first 64-wide half
    nt_store4(cosO + base + 64, cv);      // duplicated half
    nt_store4(sinO + base,      sv);
    nt_store4(sinO + base + 64, sv);
}

// Block layout (heavy-first):
//  pe3 [0,512)=32x16 | pe2 [512,1024)=32x16 | pe1 [1024,1792)=48x16 |
//  rope3 [1792,2816)=1024 | rope2 [2816,3840)=1024 | rope1 [3840,4416)=576 |
//  rope0 [4416,4672)=256 | pe0 [4672,5696)=64x16       total 5696
__global__ __launch_bounds__(256) void fused_kernel(
    const float* __restrict__ tab, const float* __restrict__ invf,
    float* __restrict__ out, float* __restrict__ cosO, float* __restrict__ sinO)
{
    int b = (int)blockIdx.x;
    if      (b < 512)  patch_body<16,32, 32, 29696>(b,         tab, out);
    else if (b < 1024) patch_body<8, 32, 64, 13312>(b - 512,   tab, out);
    else if (b < 1792) patch_body<4, 48, 48, 4096> (b - 1024,  tab, out);
    else if (b < 2816) rope_body<16,32, 32, 29696> (b - 1792,  invf, cosO, sinO);
    else if (b < 3840) rope_body<8, 32, 64, 13312> (b - 2816,  invf, cosO, sinO);
    else if (b < 4416) rope_body<4, 48, 48, 4096>  (b - 3840,  invf, cosO, sinO);
    else if (b < 4672) rope_body<1, 64, 64, 0>     (b - 4416,  invf, cosO, sinO);
    else               patch_body<1, 64, 64, 0>    (b - 4672,  tab, out);
}

extern "C" void kernel_launch(void* const* d_in, const int* in_sizes, int n_in,
                              void* d_out, int out_size, void* d_ws, size_t ws_size,
                              hipStream_t stream) {
    const float* tab  = (const float*)d_in[1];   // [1225, 1152]
    const float* invf = (const float*)d_in[2];   // [32]
    float* out = (float*)d_out;

    constexpr size_t NTOK = 46080;
    float* cosO = out + NTOK * 1152;
    float* sinO = cosO + NTOK * 128;

    fused_kernel<<<5696, 256, 0, stream>>>(tab, invf, out, cosO, sinO);
}

// Round 11
// 52.381 us; speedup vs baseline: 1.8907x; 1.8907x over previous
//
#include <hip/hip_runtime.h>

// ---------------------------------------------------------------------------
// Model_51453708206406: fast_pos_embed_interpolate + MRoPE cos/sin (f32 out).
// Outputs concatenated: [46080,1152] pe | [46080,128] cos | [46080,128] sin.
// Static grid: {1,64,64},{4,48,48},{8,32,64},{16,32,32}; merge m=2, G=35.
//
// v11: v6 dispatch shape + row-pair sharing ONLY where valid.
// linspace step 34/(H-1) < 1 iff H>35: img0 (H=64) and img1 (H=48) have
// adjacent-row floor deltas oi in {0,1} -> 6 corner loads serve 2 tokens.
// img2/img3 (H=32, step 1.097, oi can be 2 -- the v10 bug) use the plain
// proven v6 body (4 loads/token). Frame dedup + nt stores + heavy-first
// ordering kept everywhere.
// ---------------------------------------------------------------------------

typedef float fx4 __attribute__((ext_vector_type(4)));

__device__ __forceinline__ void nt_store4(float* p, fx4 v) {
    __builtin_nontemporal_store(v, (fx4*)p);
}

// ---- pe, pair-shared (REQUIRES H>35 so oi in {0,1}) -----------------------
// thread task u*288+c4, u = mb*2+j -> tokens mb*4+j (row 2bh) and
// mb*4+2+j (row 2bh+1), same col.
template <int T, int H, int W, int OFF>
__device__ __forceinline__ void pe_pair_body(int b, const float* __restrict__ tab,
                                             float* __restrict__ out) {
    static_assert(H > 35, "pair sharing needs linspace step < 1");
    constexpr int HW = H * W;
    constexpr int WB = W / 2;

    int idx = b * 256 + (int)threadIdx.x; // < (HW/2)*288 (mult of 256)
    int u   = idx / 288;                  // mb*2 + j
    int c4  = idx - u * 288;
    int j   = u & 1;
    int mb  = u >> 1;
    int bw  = mb % WB;
    int bh  = mb / WB;

    int col  = (bw << 1) + j;
    int row0 = (bh << 1);                 // token0 row; token1 row = row0+1

    float hx0 = (float)row0 * (float)(34.0 / (H - 1));
    float hx1 = (float)(row0 + 1) * (float)(34.0 / (H - 1));
    float wx  = (float)col  * (float)(34.0 / (W - 1));

    int   hf0 = (int)hx0;  float dh0 = hx0 - (float)hf0;
    int   hf1 = (int)hx1;  float dh1 = hx1 - (float)hf1;
    int   oi  = hf1 - hf0;                // 0 or 1 (H>35)
    int   wf  = (int)wx;   float dw  = wx - (float)wf;
    int   wc  = min(wf + 1, 34);
    int   r1  = min(hf0 + 1, 34);
    int   r2  = min(hf0 + 2, 34);

    // 6 corner loads serve both tokens
    const fx4 P0f = *((const fx4*)(tab + (size_t)(hf0 * 35 + wf) * 1152) + c4);
    const fx4 P0c = *((const fx4*)(tab + (size_t)(hf0 * 35 + wc) * 1152) + c4);
    const fx4 P1f = *((const fx4*)(tab + (size_t)(r1  * 35 + wf) * 1152) + c4);
    const fx4 P1c = *((const fx4*)(tab + (size_t)(r1  * 35 + wc) * 1152) + c4);
    const fx4 P2f = *((const fx4*)(tab + (size_t)(r2  * 35 + wf) * 1152) + c4);
    const fx4 P2c = *((const fx4*)(tab + (size_t)(r2  * 35 + wc) * 1152) + c4);

    float omdw = 1.f - dw;
    fx4 q0 = omdw * P0f + dw * P0c;       // column interp per row
    fx4 q1 = omdw * P1f + dw * P1c;
    fx4 q2 = omdw * P2f + dw * P2c;

    fx4 o0 = (1.f - dh0) * q0 + dh0 * q1; // token0: rows (hf0, hf0+1)
    fx4 tq = oi ? q1 : q0;                // token1: rows (hf0+oi, hf0+oi+1)
    fx4 bq = oi ? q2 : q1;
    fx4 o1 = (1.f - dh1) * tq + dh1 * bq;

    int tok0 = OFF + (mb << 2) + j;       // i=0
    int tok1 = tok0 + 2;                  // i=1

    float* d0 = out + (size_t)tok0 * 1152 + (c4 << 2);
    float* d1 = out + (size_t)tok1 * 1152 + (c4 << 2);
    #pragma unroll
    for (int f = 0; f < T; ++f) {         // frames are identical copies
        nt_store4(d0 + (size_t)f * (HW * 1152), o0);
        nt_store4(d1 + (size_t)f * (HW * 1152), o1);
    }
}

// ---- pe, plain v6 body (any H) --------------------------------------------
template <int T, int H, int W, int OFF>
__device__ __forceinline__ void pe_body(int b, const float* __restrict__ tab,
                                        float* __restrict__ out) {
    constexpr int C4 = 1152 / 4;
    constexpr int HW = H * W;
    constexpr int WB = W / 2;

    int idx = b * 256 + (int)threadIdx.x; // < HW*288 (mult of 256)
    int tok = idx / C4;
    int c4  = idx - tok * C4;

    int j  = tok & 1;
    int i  = (tok >> 1) & 1;
    int blk = tok >> 2;
    int bw = blk % WB;
    int bh = blk / WB;
    int row = (bh << 1) + i;
    int col = (bw << 1) + j;

    float hx = (float)row * (float)(34.0 / (H - 1));
    float wx = (float)col * (float)(34.0 / (W - 1));
    int hf = (int)hx, wf = (int)wx;
    float dh = hx - (float)hf, dw = wx - (float)wf;
    int hc = min(hf + 1, 34), wc = min(wf + 1, 34);

    float w00 = (1.f - dh) * (1.f - dw);
    float w01 = (1.f - dh) * dw;
    float w10 = dh * (1.f - dw);
    float w11 = dh * dw;

    const fx4 a = *((const fx4*)(tab + (hf * 35 + wf) * 1152) + c4);
    const fx4 bq= *((const fx4*)(tab + (hf * 35 + wc) * 1152) + c4);
    const fx4 c = *((const fx4*)(tab + (hc * 35 + wf) * 1152) + c4);
    const fx4 d = *((const fx4*)(tab + (hc * 35 + wc) * 1152) + c4);

    fx4 o = w00 * a + w01 * bq + w10 * c + w11 * d;

    float* dst = out + (size_t)(OFF + tok) * 1152 + (c4 << 2);
    #pragma unroll
    for (int f = 0; f < T; ++f)
        nt_store4(dst + (size_t)f * (HW * 1152), o);
}

// ---- rope: fully frame-split, one (token, channel-quad) per thread --------
template <int T, int H, int W, int OFF>
__device__ __forceinline__ void rope_body(int b, const float* __restrict__ invf,
                                          float* __restrict__ cosO,
                                          float* __restrict__ sinO) {
    constexpr int HW = H * W;
    constexpr int WB = W / 2;

    int idx = b * 256 + (int)threadIdx.x; // < T*HW*16 (mult of 256)
    int tok = idx >> 4;
    int l4  = idx & 15;
    int rem = tok % HW;

    int j  = rem & 1;
    int i  = (rem >> 1) & 1;
    int blk = rem >> 2;
    int bw = blk % WB;
    int bh = blk / WB;
    int row = (bh << 1) + i;
    int col = (bw << 1) + j;

    float fp = (float)((l4 < 8) ? row : col);
    fx4 iv = ((const fx4*)invf)[l4 & 7];

    float s0, c0, s1, c1, s2, c2, s3, c3;
    __sincosf(fp * iv.x, &s0, &c0);
    __sincosf(fp * iv.y, &s1, &c1);
    __sincosf(fp * iv.z, &s2, &c2);
    __sincosf(fp * iv.w, &s3, &c3);
    fx4 cv = {c0, c1, c2, c3};
    fx4 sv = {s0, s1, s2, s3};

    size_t base = (size_t)(OFF + tok) * 128 + (l4 << 2);
    nt_store4(cosO + base,      cv);
    nt_store4(cosO + base + 64, cv);
    nt_store4(sinO + base,      sv);
    nt_store4(sinO + base + 64, sv);
}

// Blocks: pe3 1152 (v6,64KB) | pe2 2304 (v6,32KB) | pe1 1296 (pair,32KB) |
// rope3 1024 | rope2 1024 | rope1 576 | rope0 256 (16KB each) |
// pe0 2304 (pair,8KB).  Total 9936.
__global__ __launch_bounds__(256) void fused_kernel(
    const float* __restrict__ tab, const float* __restrict__ invf,
    float* __restrict__ out, float* __restrict__ cosO, float* __restrict__ sinO)
{
    int b = (int)blockIdx.x;
    if      (b < 1152)  pe_body<16,32, 32, 29696>     (b,         tab, out);
    else if (b < 3456)  pe_body<8, 32, 64, 13312>     (b - 1152,  tab, out);
    else if (b < 4752)  pe_pair_body<4, 48, 48, 4096> (b - 3456,  tab, out);
    else if (b < 5776)  rope_body<16,32, 32, 29696>   (b - 4752,  invf, cosO, sinO);
    else if (b < 6800)  rope_body<8, 32, 64, 13312>   (b - 5776,  invf, cosO, sinO);
    else if (b < 7376)  rope_body<4, 48, 48, 4096>    (b - 6800,  invf, cosO, sinO);
    else if (b < 7632)  rope_body<1, 64, 64, 0>       (b - 7376,  invf, cosO, sinO);
    else                pe_pair_body<1, 64, 64, 0>    (b - 7632,  tab, out);
}

extern "C" void kernel_launch(void* const* d_in, const int* in_sizes, int n_in,
                              void* d_out, int out_size, void* d_ws, size_t ws_size,
                              hipStream_t stream) {
    const float* tab  = (const float*)d_in[1];   // [1225, 1152]
    const float* invf = (const float*)d_in[2];   // [32]
    float* out = (float*)d_out;

    constexpr size_t NTOK = 46080;
    float* cosO = out + NTOK * 1152;
    float* sinO = cosO + NTOK * 128;

    fused_kernel<<<9936, 256, 0, stream>>>(tab, invf, out, cosO, sinO);
}